// Round 2
// baseline (257.763 us; speedup 1.0000x reference)
//
#include <hip/hip_runtime.h>
#include <hip/hip_bf16.h>

#define TOKENS 4096
#define IN_F   4096
#define OUT_F  4096

typedef __bf16 bf16x8 __attribute__((ext_vector_type(8)));
typedef float  f32x4  __attribute__((ext_vector_type(4)));
typedef unsigned int u32;
typedef u32 u32x4 __attribute__((ext_vector_type(4)));

#define DEQ_BLOCKS 2048   // 4096 rows * 128 thread-chunks / 256
#define CVT_BLOCKS 4096   // 4096*4096 /16 /256

__device__ __forceinline__ void gld_lds16(const void* g, void* l) {
    __builtin_amdgcn_global_load_lds(
        (const __attribute__((address_space(1))) u32*)g,
        (__attribute__((address_space(3))) u32*)l,
        16, 0, 0);
}

// ---------------------------------------------------------------------------
// Fused prep: blockIdx < DEQ_BLOCKS  -> dequant int4 W (16B qweight loads,
//             32 weights/thread, 64B contiguous store)
//             else                   -> x fp32->bf16 (16 elems/thread)
// (unchanged from verified 255us version)
// ---------------------------------------------------------------------------
__global__ __launch_bounds__(256) void prep_kernel(
        const u32* __restrict__ qweight, const u32* __restrict__ qzeros,
        const float* __restrict__ scales, const float* __restrict__ x,
        __bf16* __restrict__ W, __bf16* __restrict__ A) {
    const int tid = threadIdx.x;
    if (blockIdx.x < DEQ_BLOCKS) {
        int idx4 = blockIdx.x * 256 + tid;      // 0 .. 524287
        int n  = idx4 >> 7;                     // out row (128 chunks/row)
        int p4 = (idx4 & 127) << 2;             // first packed col (0..508)
        int g  = p4 >> 4;                       // group id (constant over 4)
        u32 qz = qzeros[(n << 2) + (g >> 3)];
        float z = (float)((qz >> ((g & 7) * 4)) & 15);
        float s = scales[(n << 5) + g];
        u32x4 qw = *(const u32x4*)(qweight + (size_t)n * 512 + p4);
        __bf16* dst = W + (size_t)n * IN_F + p4 * 8;
#pragma unroll
        for (int c = 0; c < 4; ++c) {
            bf16x8 h;
#pragma unroll
            for (int j = 0; j < 8; ++j) {
                float w = ((float)((qw[c] >> (4 * j)) & 15) - z) * s;
                h[j] = (__bf16)w;
            }
            *(bf16x8*)(dst + c * 8) = h;
        }
    } else {
        int idx = (blockIdx.x - DEQ_BLOCKS) * 256 + tid;   // 0 .. 1048575
        const f32x4* xp = (const f32x4*)x + (size_t)idx * 4;
        f32x4 v0 = xp[0], v1 = xp[1], v2 = xp[2], v3 = xp[3];
        bf16x8 h0, h1;
#pragma unroll
        for (int j = 0; j < 4; ++j) {
            h0[j] = (__bf16)v0[j]; h0[4 + j] = (__bf16)v1[j];
            h1[j] = (__bf16)v2[j]; h1[4 + j] = (__bf16)v3[j];
        }
        bf16x8* ap = (bf16x8*)A + (size_t)idx * 2;
        ap[0] = h0; ap[1] = h1;
    }
}

// ---------------------------------------------------------------------------
// 256x256 8-phase GEMM (T2 swizzle + T3/T4 counted vmcnt + T5 setprio).
//   512 threads = 8 waves (2M x 4N), per-wave output 128x64, acc[8][4].
//   BK=64 split into two K-halves (kh); STATIC LDS 128 KiB:
//     lsA/lsB = [buf][kh][256 rows][32 bf16] -> 4 regions x 16KB each.
//   Chunk swizzle (both-sides involution): LDS slot s of row r holds global
//   16B k-chunk s ^ ((r>>1)&3). Frag read slot = quad ^ ((R>>1)&3):
//   each (parity,slot) pair hit by exactly 2 of 16 lanes -> 2-way = free.
//
//   Per-tile phases (kh,pm): P0=(0,0) P1=(0,1) P2=(1,0) P3=(1,1).
//   Issue ledger (1 half-tile = 2 loads/thread per phase), verified:
//     prologue L1=0Ah0 L2=0Bh0 L3=0Ah1 L4=0Bh1 L5=1Ah0 L6=1Bh0; vm8 -> L1,L2
//     t.P0 needs t.Ah0/Bh0; t.P1 vm8 completes t.Ah1/Bh1 (P2/P3 needs);
//     t.P3 vm8 completes (t+1).Ah0/Bh0 ((t+1).P0 needs).
//   Race-freedom: every STAGE targets a region whose last reads completed
//   before the nearest preceding barrier (reads are consumed by MFMA, which
//   forces lgkmcnt(0), before each closing barrier).
// ---------------------------------------------------------------------------
__global__ __launch_bounds__(512, 2) void gemm8p(
        const __bf16* __restrict__ A, const __bf16* __restrict__ B,
        const float* __restrict__ bias, float* __restrict__ C) {
    __shared__ __align__(16) char lsA[65536];
    __shared__ __align__(16) char lsB[65536];

    const int t    = threadIdx.x;
    const int lane = t & 63, wave = t >> 6;
    const int lr   = lane & 15, quad = lane >> 4;
    const int wm   = (wave >> 2) * 128;   // 2 M groups
    const int wn   = (wave & 3) * 64;     // 4 N groups

    // XCD-aware swizzle: 256 blocks, 8 XCDs, 32 contiguous tiles per XCD
    int bid = blockIdx.x;
    bid = (bid & 7) * 32 + (bid >> 3);
    const int bm = bid >> 4, bn = bid & 15;

    const __bf16* Abase = A + (size_t)bm * 256 * IN_F;
    const __bf16* Bbase = B + (size_t)bn * 256 * IN_F;

    // staging: linear LDS dest (t*16 within half-region), pre-swizzled
    // global source (rule #21: same involution on write-source and read)
    const int srow0 = t >> 2;               // rows 0..127
    const int srow1 = 128 + (t >> 2);       // rows 128..255
    const int scol0 = ((t & 3) ^ ((srow0 >> 1) & 3)) * 8;   // elements
    const int scol1 = ((t & 3) ^ ((srow1 >> 1) & 3)) * 8;

#define STAGE(OPBASE, LS, KT, KH, BUF) do {                                  \
    int _kb = (((KT) & 63) * 64 + (KH) * 32);                                \
    gld_lds16(OPBASE + (size_t)srow0 * IN_F + _kb + scol0,                   \
              LS + ((BUF) * 2 + (KH)) * 16384 + t * 16);                     \
    gld_lds16(OPBASE + (size_t)srow1 * IN_F + _kb + scol1,                   \
              LS + ((BUF) * 2 + (KH)) * 16384 + 8192 + t * 16);              \
} while (0)

    bf16x8 af[4], bfr[4];
    f32x4 acc[8][4] = {};

#define LDA4(PM, KH, BUF) do {                                               \
    _Pragma("unroll")                                                        \
    for (int i = 0; i < 4; ++i) {                                            \
        const int R = wm + (PM) * 64 + i * 16 + lr;                          \
        af[i] = *(const bf16x8*)(lsA + ((BUF) * 2 + (KH)) * 16384 +          \
                                 R * 64 + ((quad ^ ((R >> 1) & 3)) * 16));   \
    }                                                                        \
} while (0)

#define LDB4(KH, BUF) do {                                                   \
    _Pragma("unroll")                                                        \
    for (int j = 0; j < 4; ++j) {                                            \
        const int R = wn + j * 16 + lr;                                      \
        bfr[j] = *(const bf16x8*)(lsB + ((BUF) * 2 + (KH)) * 16384 +         \
                                  R * 64 + ((quad ^ ((R >> 1) & 3)) * 16));  \
    }                                                                        \
} while (0)

#define MFMA16(PM) do {                                                      \
    _Pragma("unroll")                                                        \
    for (int i = 0; i < 4; ++i)                                              \
    _Pragma("unroll")                                                        \
    for (int j = 0; j < 4; ++j)                                              \
        acc[(PM) * 4 + i][j] = __builtin_amdgcn_mfma_f32_16x16x32_bf16(      \
            af[i], bfr[j], acc[(PM) * 4 + i][j], 0, 0, 0);                   \
} while (0)

// s_barrier intrinsic is IntrNoMem -> bracket with compiler-only fences so
// LDS reads/stage writes cannot be reordered across it (zero instructions).
#define FENCE() asm volatile("" ::: "memory")
#define BAR()  do { FENCE(); __builtin_amdgcn_s_barrier(); FENCE(); } while (0)
#define VM8()  asm volatile("s_waitcnt vmcnt(8)" ::: "memory")
#define PRIO(x) __builtin_amdgcn_s_setprio(x)

    // prologue: 0.Ah0 0.Bh0 0.Ah1 0.Bh1 1.Ah0 1.Bh0 (12 loads), wait 8
    STAGE(Abase, lsA, 0, 0, 0);
    STAGE(Bbase, lsB, 0, 0, 0);
    STAGE(Abase, lsA, 0, 1, 0);
    STAGE(Bbase, lsB, 0, 1, 0);
    STAGE(Abase, lsA, 1, 0, 1);
    STAGE(Bbase, lsB, 1, 0, 1);
    VM8();
    BAR();

#define TILE(KT, B) do {                                                     \
    /* P0: kh0 pm0 — issue (t+1).A.h1 into other buf (last read t-1.P3) */   \
    LDB4(0, B); LDA4(0, 0, B);                                               \
    STAGE(Abase, lsA, (KT) + 1, 1, 1 - (B));                                 \
    BAR(); PRIO(1); MFMA16(0); PRIO(0); BAR();                               \
    /* P1: kh0 pm1 (B frags reused) — issue (t+1).B.h1 */                    \
    LDA4(1, 0, B);                                                           \
    STAGE(Bbase, lsB, (KT) + 1, 1, 1 - (B));                                 \
    BAR(); PRIO(1); MFMA16(1); PRIO(0); VM8(); BAR();                        \
    /* P2: kh1 pm0 — issue (t+2).A.h0 into own buf (h0 reads ended P1) */    \
    LDB4(1, B); LDA4(0, 1, B);                                               \
    STAGE(Abase, lsA, (KT) + 2, 0, B);                                       \
    BAR(); PRIO(1); MFMA16(0); PRIO(0); BAR();                               \
    /* P3: kh1 pm1 — issue (t+2).B.h0 */                                     \
    LDA4(1, 1, B);                                                           \
    STAGE(Bbase, lsB, (KT) + 2, 0, B);                                       \
    BAR(); PRIO(1); MFMA16(1); PRIO(0); VM8(); BAR();                        \
} while (0)

    for (int kt = 0; kt < 64; kt += 2) {
        TILE(kt, 0);
        TILE(kt + 1, 1);
    }

    asm volatile("s_waitcnt vmcnt(0)" ::: "memory");

    // epilogue: C/D layout col = lane&15, row = (lane>>4)*4 + reg
    const int row0 = bm * 256 + wm + quad * 4;
    const int col0 = bn * 256 + wn + lr;
#pragma unroll
    for (int j = 0; j < 4; ++j) {
        const int col = col0 + j * 16;
        const float bv = bias[col];
#pragma unroll
        for (int i = 0; i < 8; ++i) {
            const int row = row0 + i * 16;
#pragma unroll
            for (int r = 0; r < 4; ++r)
                C[(size_t)(row + r) * OUT_F + col] = acc[i][j][r] + bv;
        }
    }
}

extern "C" void kernel_launch(void* const* d_in, const int* in_sizes, int n_in,
                              void* d_out, int out_size, void* d_ws, size_t ws_size,
                              hipStream_t stream) {
    (void)in_sizes; (void)n_in; (void)out_size; (void)ws_size;
    const float* x       = (const float*)d_in[0];
    const u32*   qweight = (const u32*)d_in[1];
    const u32*   qzeros  = (const u32*)d_in[2];
    const float* scales  = (const float*)d_in[3];
    const float* bias    = (const float*)d_in[4];
    float* out = (float*)d_out;

    __bf16* W   = (__bf16*)d_ws;                                     // 32 MB
    __bf16* Abf = (__bf16*)((char*)d_ws + (size_t)OUT_F * IN_F * 2); // 32 MB

    prep_kernel<<<dim3(DEQ_BLOCKS + CVT_BLOCKS), dim3(256), 0, stream>>>(
        qweight, qzeros, scales, x, W, Abf);
    gemm8p<<<dim3(256), dim3(512), 0, stream>>>(Abf, W, bias, out);
}

// Round 3
// 247.496 us; speedup vs baseline: 1.0415x; 1.0415x over previous
//
#include <hip/hip_runtime.h>
#include <hip/hip_bf16.h>

#define TOKENS 4096
#define IN_F   4096
#define OUT_F  4096

typedef __bf16 bf16x8 __attribute__((ext_vector_type(8)));
typedef float  f32x4  __attribute__((ext_vector_type(4)));
typedef unsigned int u32;
typedef u32 u32x4 __attribute__((ext_vector_type(4)));

#define DEQ_BLOCKS 2048   // 4096 rows * 128 thread-chunks / 256
#define CVT_BLOCKS 4096   // 4096*4096 /16 /256

__device__ __forceinline__ void gld_lds16(const void* g, void* l) {
    __builtin_amdgcn_global_load_lds(
        (const __attribute__((address_space(1))) u32*)g,
        (__attribute__((address_space(3))) u32*)l,
        16, 0, 0);
}

// ---------------------------------------------------------------------------
// Fused prep (unchanged from verified 255us version)
// ---------------------------------------------------------------------------
__global__ __launch_bounds__(256) void prep_kernel(
        const u32* __restrict__ qweight, const u32* __restrict__ qzeros,
        const float* __restrict__ scales, const float* __restrict__ x,
        __bf16* __restrict__ W, __bf16* __restrict__ A) {
    const int tid = threadIdx.x;
    if (blockIdx.x < DEQ_BLOCKS) {
        int idx4 = blockIdx.x * 256 + tid;      // 0 .. 524287
        int n  = idx4 >> 7;                     // out row (128 chunks/row)
        int p4 = (idx4 & 127) << 2;             // first packed col (0..508)
        int g  = p4 >> 4;                       // group id (constant over 4)
        u32 qz = qzeros[(n << 2) + (g >> 3)];
        float z = (float)((qz >> ((g & 7) * 4)) & 15);
        float s = scales[(n << 5) + g];
        u32x4 qw = *(const u32x4*)(qweight + (size_t)n * 512 + p4);
        __bf16* dst = W + (size_t)n * IN_F + p4 * 8;
#pragma unroll
        for (int c = 0; c < 4; ++c) {
            bf16x8 h;
#pragma unroll
            for (int j = 0; j < 8; ++j) {
                float w = ((float)((qw[c] >> (4 * j)) & 15) - z) * s;
                h[j] = (__bf16)w;
            }
            *(bf16x8*)(dst + c * 8) = h;
        }
    } else {
        int idx = (blockIdx.x - DEQ_BLOCKS) * 256 + tid;   // 0 .. 1048575
        const f32x4* xp = (const f32x4*)x + (size_t)idx * 4;
        f32x4 v0 = xp[0], v1 = xp[1], v2 = xp[2], v3 = xp[3];
        bf16x8 h0, h1;
#pragma unroll
        for (int j = 0; j < 4; ++j) {
            h0[j] = (__bf16)v0[j]; h0[4 + j] = (__bf16)v1[j];
            h1[j] = (__bf16)v2[j]; h1[4 + j] = (__bf16)v3[j];
        }
        bf16x8* ap = (bf16x8*)A + (size_t)idx * 2;
        ap[0] = h0; ap[1] = h1;
    }
}

// ---------------------------------------------------------------------------
// 256x256 8-phase GEMM, round 3: fragment LDS reads via INLINE-ASM
// ds_read_b128 so the backend waitcnt pass cannot see a ds_read that aliases
// the global_load_lds destinations (theory: it was inserting vmcnt(0) before
// every phase's reads, defeating the counted-vmcnt pipeline -> 600cyc/phase
// stall observed in round 2).
//   Layout/swizzle unchanged: lsA/lsB [buf][kh][256 rows][32 bf16];
//   slot s of row r holds global chunk s ^ ((r>>1)&3); read slot =
//   quad ^ ((lr>>1)&3) (independent of row base since 16 | row-base).
//
//   Phases per K-tile t (buf B=t&1): P0=(kh0,pm0) P1=(kh0,pm1)
//   P2=(kh1,pm0) P3=(kh1,pm1). Stage issue: P0->(t+1).Ah1, P1->(t+1).Bh1,
//   P2->(t+2).Ah0, P3->(t+2).Bh0. ONE counted wait per tile: vmcnt(4) at
//   P3 (allowed outstanding = t+2 prefetches) => all of tile t+1's buffer
//   (staged (t-1).P2/P3 + t.P0/P1) complete before tile t+1 opens.
//   Race-freedom: each STAGE targets a region whose last ds_read completed
//   before the nearest preceding barrier (kh0 regions last read in P0/P1,
//   restaged in P2/P3; opposite-buf kh1 last read in prev tile's P2/P3).
// ---------------------------------------------------------------------------
__global__ __launch_bounds__(512, 2) void gemm8p(
        const __bf16* __restrict__ A, const __bf16* __restrict__ B,
        const float* __restrict__ bias, float* __restrict__ C) {
    __shared__ __align__(16) char lsA[65536];
    __shared__ __align__(16) char lsB[65536];

    const int t    = threadIdx.x;
    const int lane = t & 63, wave = t >> 6;
    const int lr   = lane & 15, quad = lane >> 4;
    const int wm   = (wave >> 2) * 128;   // 2 M groups
    const int wn   = (wave & 3) * 64;     // 4 N groups

    // XCD-aware swizzle: 256 blocks, 8 XCDs, 32 contiguous tiles per XCD
    int bid = blockIdx.x;
    bid = (bid & 7) * 32 + (bid >> 3);
    const int bm = bid >> 4, bn = bid & 15;

    const __bf16* Abase = A + (size_t)bm * 256 * IN_F;
    const __bf16* Bbase = B + (size_t)bn * 256 * IN_F;

    // staging: linear LDS dest, pre-swizzled global source (rule #21)
    const int srow0 = t >> 2;               // rows 0..127
    const int srow1 = 128 + (t >> 2);       // rows 128..255
    const int scol0 = ((t & 3) ^ ((srow0 >> 1) & 3)) * 8;   // elements
    const int scol1 = ((t & 3) ^ ((srow1 >> 1) & 3)) * 8;

#define STAGE(OPBASE, LS, KT, KH, BUF) do {                                  \
    int _kb = (((KT) & 63) * 64 + (KH) * 32);                                \
    gld_lds16(OPBASE + (size_t)srow0 * IN_F + _kb + scol0,                   \
              LS + ((BUF) * 2 + (KH)) * 16384 + t * 16);                     \
    gld_lds16(OPBASE + (size_t)srow1 * IN_F + _kb + scol1,                   \
              LS + ((BUF) * 2 + (KH)) * 16384 + 8192 + t * 16);              \
} while (0)

    // LDS byte-offset bases for asm ds_read (addrspace(3) offsets are 32-bit)
    const u32 slot16 = (u32)((quad ^ ((lr >> 1) & 3)) * 16);
    const u32 lsA0 = (u32)(size_t)(__attribute__((address_space(3))) char*)lsA;
    const u32 lsB0 = (u32)(size_t)(__attribute__((address_space(3))) char*)lsB;
    const u32 aA = lsA0 + (u32)((wm + lr) * 64) + slot16;
    const u32 aB = lsB0 + (u32)((wn + lr) * 64) + slot16;

    bf16x8 af[4], bfr[4];
    f32x4 acc[8][4] = {};

// inline-asm ds_read_b128: invisible to SIInsertWaitcnts (no auto vmcnt
// drain vs global_load_lds); ordering vs barriers via volatile-asm program
// order; returns fenced by explicit lgkmcnt(0)+sched_barrier (rule #18).
#define DSR(dst, base, OFF) do {                                             \
    u32x4 _r;                                                                \
    asm volatile("ds_read_b128 %0, %1 offset:%2"                             \
                 : "=v"(_r) : "v"(base), "n"(OFF));                          \
    dst = __builtin_bit_cast(bf16x8, _r);                                    \
} while (0)

#define LDA4(PM, KH, BUF) do {                                               \
    DSR(af[0], aA, (((BUF)*2+(KH))*16384 + (PM)*4096 + 0*1024));             \
    DSR(af[1], aA, (((BUF)*2+(KH))*16384 + (PM)*4096 + 1*1024));             \
    DSR(af[2], aA, (((BUF)*2+(KH))*16384 + (PM)*4096 + 2*1024));             \
    DSR(af[3], aA, (((BUF)*2+(KH))*16384 + (PM)*4096 + 3*1024));             \
} while (0)

#define LDB4(KH, BUF) do {                                                   \
    DSR(bfr[0], aB, (((BUF)*2+(KH))*16384 + 0*1024));                        \
    DSR(bfr[1], aB, (((BUF)*2+(KH))*16384 + 1*1024));                        \
    DSR(bfr[2], aB, (((BUF)*2+(KH))*16384 + 2*1024));                        \
    DSR(bfr[3], aB, (((BUF)*2+(KH))*16384 + 3*1024));                        \
} while (0)

#define MFMA16(PM) do {                                                      \
    _Pragma("unroll")                                                        \
    for (int i = 0; i < 4; ++i)                                              \
    _Pragma("unroll")                                                        \
    for (int j = 0; j < 4; ++j)                                              \
        acc[(PM) * 4 + i][j] = __builtin_amdgcn_mfma_f32_16x16x32_bf16(      \
            af[i], bfr[j], acc[(PM) * 4 + i][j], 0, 0, 0);                   \
} while (0)

#define FENCE() asm volatile("" ::: "memory")
#define BAR()  do { FENCE(); __builtin_amdgcn_s_barrier(); FENCE(); } while (0)
#define VM4()  asm volatile("s_waitcnt vmcnt(4)" ::: "memory")
#define PRIO(x) __builtin_amdgcn_s_setprio(x)
// opening barrier + lgkm drain for this phase's asm ds_reads + sched fence
#define OPENB() do { BAR();                                                  \
    asm volatile("s_waitcnt lgkmcnt(0)" ::: "memory");                       \
    __builtin_amdgcn_sched_barrier(0); } while (0)

    // prologue: 0.Ah0 0.Bh0 0.Ah1 0.Bh1 1.Ah0 1.Bh0 (12 loads);
    // vmcnt(4) completes all of tile 0's buffer, leaves tile1 h0 in flight.
    STAGE(Abase, lsA, 0, 0, 0);
    STAGE(Bbase, lsB, 0, 0, 0);
    STAGE(Abase, lsA, 0, 1, 0);
    STAGE(Bbase, lsB, 0, 1, 0);
    STAGE(Abase, lsA, 1, 0, 1);
    STAGE(Bbase, lsB, 1, 0, 1);
    VM4();
    BAR();

#define TILE(KT, B) do {                                                     \
    /* P0: kh0 pm0 — stage (t+1).A.h1 into other buf */                      \
    LDB4(0, B); LDA4(0, 0, B);                                               \
    STAGE(Abase, lsA, (KT) + 1, 1, 1 - (B));                                 \
    OPENB(); PRIO(1); MFMA16(0); PRIO(0); BAR();                             \
    /* P1: kh0 pm1 (B frags reused) — stage (t+1).B.h1 */                    \
    LDA4(1, 0, B);                                                           \
    STAGE(Bbase, lsB, (KT) + 1, 1, 1 - (B));                                 \
    OPENB(); PRIO(1); MFMA16(1); PRIO(0); BAR();                             \
    /* P2: kh1 pm0 — stage (t+2).A.h0 into own buf (kh0 reads done P1) */    \
    LDB4(1, B); LDA4(0, 1, B);                                               \
    STAGE(Abase, lsA, (KT) + 2, 0, B);                                       \
    OPENB(); PRIO(1); MFMA16(0); PRIO(0); BAR();                             \
    /* P3: kh1 pm1 — stage (t+2).B.h0; ONE counted wait per tile */          \
    LDA4(1, 1, B);                                                           \
    STAGE(Bbase, lsB, (KT) + 2, 0, B);                                       \
    OPENB(); PRIO(1); MFMA16(1); PRIO(0); VM4(); BAR();                      \
} while (0)

    for (int kt = 0; kt < 64; kt += 2) {
        TILE(kt, 0);
        TILE(kt + 1, 1);
    }

    asm volatile("s_waitcnt vmcnt(0)" ::: "memory");

    // epilogue: C/D layout col = lane&15, row = (lane>>4)*4 + reg
    const int row0 = bm * 256 + wm + quad * 4;
    const int col0 = bn * 256 + wn + lr;
#pragma unroll
    for (int j = 0; j < 4; ++j) {
        const int col = col0 + j * 16;
        const float bv = bias[col];
#pragma unroll
        for (int i = 0; i < 8; ++i) {
            const int row = row0 + i * 16;
#pragma unroll
            for (int r = 0; r < 4; ++r)
                C[(size_t)(row + r) * OUT_F + col] = acc[i][j][r] + bv;
        }
    }
}

extern "C" void kernel_launch(void* const* d_in, const int* in_sizes, int n_in,
                              void* d_out, int out_size, void* d_ws, size_t ws_size,
                              hipStream_t stream) {
    (void)in_sizes; (void)n_in; (void)out_size; (void)ws_size;
    const float* x       = (const float*)d_in[0];
    const u32*   qweight = (const u32*)d_in[1];
    const u32*   qzeros  = (const u32*)d_in[2];
    const float* scales  = (const float*)d_in[3];
    const float* bias    = (const float*)d_in[4];
    float* out = (float*)d_out;

    __bf16* W   = (__bf16*)d_ws;                                     // 32 MB
    __bf16* Abf = (__bf16*)((char*)d_ws + (size_t)OUT_F * IN_F * 2); // 32 MB

    prep_kernel<<<dim3(DEQ_BLOCKS + CVT_BLOCKS), dim3(256), 0, stream>>>(
        qweight, qzeros, scales, x, W, Abf);
    gemm8p<<<dim3(256), dim3(512), 0, stream>>>(Abf, W, bias, out);
}

// Round 4
// 240.212 us; speedup vs baseline: 1.0731x; 1.0303x over previous
//
#include <hip/hip_runtime.h>
#include <hip/hip_bf16.h>

#define TOKENS 4096
#define IN_F   4096
#define OUT_F  4096

typedef __bf16 bf16x8 __attribute__((ext_vector_type(8)));
typedef float  f32x4  __attribute__((ext_vector_type(4)));
typedef unsigned int u32;
typedef u32 u32x4 __attribute__((ext_vector_type(4)));

#define DEQ_BLOCKS 2048   // 4096 rows * 128 thread-chunks / 256
#define CVT_BLOCKS 4096   // 4096*4096 /16 /256

__device__ __forceinline__ void gld_lds16(const void* g, void* l) {
    __builtin_amdgcn_global_load_lds(
        (const __attribute__((address_space(1))) u32*)g,
        (__attribute__((address_space(3))) u32*)l,
        16, 0, 0);
}

// ---------------------------------------------------------------------------
// Fused prep (unchanged from verified 255us version)
// ---------------------------------------------------------------------------
__global__ __launch_bounds__(256) void prep_kernel(
        const u32* __restrict__ qweight, const u32* __restrict__ qzeros,
        const float* __restrict__ scales, const float* __restrict__ x,
        __bf16* __restrict__ W, __bf16* __restrict__ A) {
    const int tid = threadIdx.x;
    if (blockIdx.x < DEQ_BLOCKS) {
        int idx4 = blockIdx.x * 256 + tid;      // 0 .. 524287
        int n  = idx4 >> 7;                     // out row (128 chunks/row)
        int p4 = (idx4 & 127) << 2;             // first packed col (0..508)
        int g  = p4 >> 4;                       // group id (constant over 4)
        u32 qz = qzeros[(n << 2) + (g >> 3)];
        float z = (float)((qz >> ((g & 7) * 4)) & 15);
        float s = scales[(n << 5) + g];
        u32x4 qw = *(const u32x4*)(qweight + (size_t)n * 512 + p4);
        __bf16* dst = W + (size_t)n * IN_F + p4 * 8;
#pragma unroll
        for (int c = 0; c < 4; ++c) {
            bf16x8 h;
#pragma unroll
            for (int j = 0; j < 8; ++j) {
                float w = ((float)((qw[c] >> (4 * j)) & 15) - z) * s;
                h[j] = (__bf16)w;
            }
            *(bf16x8*)(dst + c * 8) = h;
        }
    } else {
        int idx = (blockIdx.x - DEQ_BLOCKS) * 256 + tid;   // 0 .. 1048575
        const f32x4* xp = (const f32x4*)x + (size_t)idx * 4;
        f32x4 v0 = xp[0], v1 = xp[1], v2 = xp[2], v3 = xp[3];
        bf16x8 h0, h1;
#pragma unroll
        for (int j = 0; j < 4; ++j) {
            h0[j] = (__bf16)v0[j]; h0[4 + j] = (__bf16)v1[j];
            h1[j] = (__bf16)v2[j]; h1[4 + j] = (__bf16)v3[j];
        }
        bf16x8* ap = (bf16x8*)A + (size_t)idx * 2;
        ap[0] = h0; ap[1] = h1;
    }
}

// ---------------------------------------------------------------------------
// 256x256 GEMM, round 4: LDS-read / MFMA OVERLAP via in-burst read injection.
//   Round-2/3 model: phase = [48 ds_read_b128 x 12cyc = 576] -> bar ->
//   [MFMA 515] serial = 1091 cyc -> MfmaUtil 47% (measured 47.5). Fix: next
//   phase's reads are injected INSIDE the MFMA burst right after the last
//   MFMA using the register they overwrite -> single af/bfr sets (no VGPR
//   growth), LDS unit chews during the MFMA burst.
//   Burst orders: P0/P2 i-major (af[i] dead after group i -> inject af[i]);
//   P1/P3 j-major (bfr[j] dead after group j -> inject bfr[j]; af tail x4).
//   Frag circular schedule (single sets):
//     pre-loop: af=pm0kh0, bfr=kh0 | P0 burst(pm0) injects af<-pm1kh0
//     P1 burst(pm1) injects bfr<-kh1, tail af<-pm0kh1
//     P2 burst(pm0) injects af<-pm1kh1 | P3 burst(pm1) injects bfr<-kh0',
//     tail af<-pm0kh0'  -> next tile P0.
//   ONE barrier per phase (4/K-tile). Write-after-read safety for (reads in
//   p) vs (STAGE in p+1), per region (op,kh,buf), tile t buf B:
//     P0 reads (A,kh0,B)      vs P1 STAGE (B,kh1,1-B)  : disjoint
//     P1 reads (B+A,kh1,B)    vs P2 STAGE (A,kh0,B)    : kh differs
//     P2 reads (A,kh1,B)      vs P3 STAGE (B,kh0,B)    : op differs
//     P3 reads (B+A,kh0,1-B)  vs t+1.P0 STAGE (A,kh1,B): buf differs
//   (STAGE in p+2 is safe: reads drain at p+1's lgkmcnt(0) before p+1's bar.)
//   vmcnt ledger (2 loads/STAGE, FIFO):
//     t.P2 VM6: queue [(t+1)Ah0,(t+1)Bh0,(t+1)Ah1,(t+1)Bh1,(t+2)Ah0]=10
//       -> completes (t+1).kh0, read in t.P3 body (after P2's barrier). OK
//     t.P3 VM4: queue [(t+1)Ah1,(t+1)Bh1,(t+2)Ah0,(t+2)Bh0]=8
//       -> completes (t+1).kh1, first read in (t+1).P1 body. OK
//   Reads of staged data always follow [wait in phase p] + [p's barrier].
// ---------------------------------------------------------------------------
__global__ __launch_bounds__(512, 2) void gemm8p(
        const __bf16* __restrict__ A, const __bf16* __restrict__ B,
        const float* __restrict__ bias, float* __restrict__ C) {
    __shared__ __align__(16) char lsA[65536];
    __shared__ __align__(16) char lsB[65536];

    const int t    = threadIdx.x;
    const int lane = t & 63, wave = t >> 6;
    const int lr   = lane & 15, quad = lane >> 4;
    const int wm   = (wave >> 2) * 128;   // 2 M groups
    const int wn   = (wave & 3) * 64;     // 4 N groups

    // XCD-aware swizzle: 256 blocks, 8 XCDs, 32 contiguous tiles per XCD
    int bid = blockIdx.x;
    bid = (bid & 7) * 32 + (bid >> 3);
    const int bm = bid >> 4, bn = bid & 15;

    const __bf16* Abase = A + (size_t)bm * 256 * IN_F;
    const __bf16* Bbase = B + (size_t)bn * 256 * IN_F;

    // staging: linear LDS dest, pre-swizzled global source (rule #21)
    const int srow0 = t >> 2;               // rows 0..127
    const int srow1 = 128 + (t >> 2);       // rows 128..255
    const int scol0 = ((t & 3) ^ ((srow0 >> 1) & 3)) * 8;   // elements
    const int scol1 = ((t & 3) ^ ((srow1 >> 1) & 3)) * 8;

#define STAGE(OPBASE, LS, KT, KH, BUF) do {                                  \
    int _kb = (((KT) & 63) * 64 + (KH) * 32);                                \
    gld_lds16(OPBASE + (size_t)srow0 * IN_F + _kb + scol0,                   \
              LS + ((BUF) * 2 + (KH)) * 16384 + t * 16);                     \
    gld_lds16(OPBASE + (size_t)srow1 * IN_F + _kb + scol1,                   \
              LS + ((BUF) * 2 + (KH)) * 16384 + 8192 + t * 16);              \
} while (0)

    // LDS byte bases for asm ds_read; read slot = quad ^ ((lr>>1)&3)
    // (row bases are multiples of 16 so (R>>1)&3 == (lr>>1)&3 pattern holds)
    const u32 slot16 = (u32)((quad ^ ((lr >> 1) & 3)) * 16);
    const u32 lsA0 = (u32)(size_t)(__attribute__((address_space(3))) char*)lsA;
    const u32 lsB0 = (u32)(size_t)(__attribute__((address_space(3))) char*)lsB;
    const u32 aA = lsA0 + (u32)((wm + lr) * 64) + slot16;
    const u32 aB = lsB0 + (u32)((wn + lr) * 64) + slot16;

    bf16x8 af[4], bfr[4];
    f32x4 acc[8][4] = {};

// region byte offsets within lsA/lsB: [buf][kh] x 16 KiB; pm adds 4096
#define RA(BUF, KH) (((BUF) * 2 + (KH)) * 16384)
#define RB(BUF, KH) (((BUF) * 2 + (KH)) * 16384)

// inline-asm ds_read_b128 (opaque to waitcnt pass; manual lgkm discipline)
#define DSR(dst, base, OFF) do {                                             \
    u32x4 _r;                                                                \
    asm volatile("ds_read_b128 %0, %1 offset:%2"                             \
                 : "=v"(_r) : "v"(base), "n"(OFF));                          \
    dst = __builtin_bit_cast(bf16x8, _r);                                    \
} while (0)

#define MFMA4_I(PM, I) do {                                                  \
    _Pragma("unroll")                                                        \
    for (int j = 0; j < 4; ++j)                                              \
        acc[(PM) * 4 + (I)][j] = __builtin_amdgcn_mfma_f32_16x16x32_bf16(    \
            af[(I)], bfr[j], acc[(PM) * 4 + (I)][j], 0, 0, 0);               \
} while (0)

#define MFMA4_J(PM, J) do {                                                  \
    _Pragma("unroll")                                                        \
    for (int i = 0; i < 4; ++i)                                              \
        acc[(PM) * 4 + i][(J)] = __builtin_amdgcn_mfma_f32_16x16x32_bf16(    \
            af[i], bfr[(J)], acc[(PM) * 4 + i][(J)], 0, 0, 0);               \
} while (0)

#define FENCE() asm volatile("" ::: "memory")
#define BAR()  do { FENCE(); __builtin_amdgcn_s_barrier(); FENCE(); } while (0)
#define VM6()  asm volatile("s_waitcnt vmcnt(6)" ::: "memory")
#define VM4()  asm volatile("s_waitcnt vmcnt(4)" ::: "memory")
#define PRIO(x) __builtin_amdgcn_s_setprio(x)
#define SB()   __builtin_amdgcn_sched_barrier(0)
#define LGKM0SB() do {                                                       \
    asm volatile("s_waitcnt lgkmcnt(0)" ::: "memory"); SB(); } while (0)

// P0: MFMA pm0 (af=pm0kh0, bfr=kh0), i-major; inject af[i] <- pm1 kh0
#define P0_BODY(KT, B) do {                                                  \
    STAGE(Abase, lsA, (KT) + 1, 1, 1 - (B));                                 \
    LGKM0SB(); PRIO(1);                                                      \
    MFMA4_I(0,0); SB(); DSR(af[0], aA, RA(B,0)+4096+0*1024); SB();           \
    MFMA4_I(0,1); SB(); DSR(af[1], aA, RA(B,0)+4096+1*1024); SB();           \
    MFMA4_I(0,2); SB(); DSR(af[2], aA, RA(B,0)+4096+2*1024); SB();           \
    MFMA4_I(0,3); SB(); DSR(af[3], aA, RA(B,0)+4096+3*1024); SB();           \
    PRIO(0); BAR();                                                          \
} while (0)

// P1: MFMA pm1 (af=pm1kh0, bfr=kh0), j-major; inject bfr[j] <- kh1;
//     tail af <- pm0 kh1
#define P1_BODY(KT, B) do {                                                  \
    STAGE(Bbase, lsB, (KT) + 1, 1, 1 - (B));                                 \
    LGKM0SB(); PRIO(1);                                                      \
    MFMA4_J(1,0); SB(); DSR(bfr[0], aB, RB(B,1)+0*1024); SB();               \
    MFMA4_J(1,1); SB(); DSR(bfr[1], aB, RB(B,1)+1*1024); SB();               \
    MFMA4_J(1,2); SB(); DSR(bfr[2], aB, RB(B,1)+2*1024); SB();               \
    MFMA4_J(1,3); SB(); DSR(bfr[3], aB, RB(B,1)+3*1024); SB();               \
    DSR(af[0], aA, RA(B,1)+0*1024); DSR(af[1], aA, RA(B,1)+1*1024);          \
    DSR(af[2], aA, RA(B,1)+2*1024); DSR(af[3], aA, RA(B,1)+3*1024);          \
    PRIO(0); BAR();                                                          \
} while (0)

// P2: MFMA pm0 (af=pm0kh1, bfr=kh1), i-major; inject af[i] <- pm1 kh1; VM6
#define P2_BODY(KT, B) do {                                                  \
    STAGE(Abase, lsA, (KT) + 2, 0, (B));                                     \
    LGKM0SB(); PRIO(1);                                                      \
    MFMA4_I(0,0); SB(); DSR(af[0], aA, RA(B,1)+4096+0*1024); SB();           \
    MFMA4_I(0,1); SB(); DSR(af[1], aA, RA(B,1)+4096+1*1024); SB();           \
    MFMA4_I(0,2); SB(); DSR(af[2], aA, RA(B,1)+4096+2*1024); SB();           \
    MFMA4_I(0,3); SB(); DSR(af[3], aA, RA(B,1)+4096+3*1024); SB();           \
    PRIO(0); VM6(); BAR();                                                   \
} while (0)

// P3: MFMA pm1 (af=pm1kh1, bfr=kh1), j-major; inject bfr[j] <- kh0 buf';
//     tail af <- pm0 kh0 buf'; VM4
#define P3_BODY(KT, B) do {                                                  \
    STAGE(Bbase, lsB, (KT) + 2, 0, (B));                                     \
    LGKM0SB(); PRIO(1);                                                      \
    MFMA4_J(1,0); SB(); DSR(bfr[0], aB, RB(1-(B),0)+0*1024); SB();           \
    MFMA4_J(1,1); SB(); DSR(bfr[1], aB, RB(1-(B),0)+1*1024); SB();           \
    MFMA4_J(1,2); SB(); DSR(bfr[2], aB, RB(1-(B),0)+2*1024); SB();           \
    MFMA4_J(1,3); SB(); DSR(bfr[3], aB, RB(1-(B),0)+3*1024); SB();           \
    DSR(af[0], aA, RA(1-(B),0)+0*1024); DSR(af[1], aA, RA(1-(B),0)+1*1024);  \
    DSR(af[2], aA, RA(1-(B),0)+2*1024); DSR(af[3], aA, RA(1-(B),0)+3*1024);  \
    PRIO(0); VM4(); BAR();                                                   \
} while (0)

    // prologue: stage tile0 fully + tile1 kh0 (12 loads);
    // vmcnt(4) completes all of tile0, leaves tile1.kh0 in flight.
    STAGE(Abase, lsA, 0, 0, 0);
    STAGE(Bbase, lsB, 0, 0, 0);
    STAGE(Abase, lsA, 0, 1, 0);
    STAGE(Bbase, lsB, 0, 1, 0);
    STAGE(Abase, lsA, 1, 0, 1);
    STAGE(Bbase, lsB, 1, 0, 1);
    VM4();
    BAR();
    // preload frags for 0.P0: bfr = kh0 buf0, af = pm0 kh0 buf0
    DSR(bfr[0], aB, RB(0,0)+0*1024); DSR(bfr[1], aB, RB(0,0)+1*1024);
    DSR(bfr[2], aB, RB(0,0)+2*1024); DSR(bfr[3], aB, RB(0,0)+3*1024);
    DSR(af[0], aA, RA(0,0)+0*1024);  DSR(af[1], aA, RA(0,0)+1*1024);
    DSR(af[2], aA, RA(0,0)+2*1024);  DSR(af[3], aA, RA(0,0)+3*1024);

    for (int kt = 0; kt < 64; kt += 2) {
        P0_BODY(kt, 0); P1_BODY(kt, 0); P2_BODY(kt, 0); P3_BODY(kt, 0);
        P0_BODY(kt + 1, 1); P1_BODY(kt + 1, 1);
        P2_BODY(kt + 1, 1); P3_BODY(kt + 1, 1);
    }

    asm volatile("s_waitcnt vmcnt(0) lgkmcnt(0)" ::: "memory");

    // epilogue: C/D layout col = lane&15, row = (lane>>4)*4 + reg
    const int row0 = bm * 256 + wm + quad * 4;
    const int col0 = bn * 256 + wn + lr;
#pragma unroll
    for (int j = 0; j < 4; ++j) {
        const int col = col0 + j * 16;
        const float bv = bias[col];
#pragma unroll
        for (int i = 0; i < 8; ++i) {
            const int row = row0 + i * 16;
#pragma unroll
            for (int r = 0; r < 4; ++r)
                C[(size_t)(row + r) * OUT_F + col] = acc[i][j][r] + bv;
        }
    }
}

extern "C" void kernel_launch(void* const* d_in, const int* in_sizes, int n_in,
                              void* d_out, int out_size, void* d_ws, size_t ws_size,
                              hipStream_t stream) {
    (void)in_sizes; (void)n_in; (void)out_size; (void)ws_size;
    const float* x       = (const float*)d_in[0];
    const u32*   qweight = (const u32*)d_in[1];
    const u32*   qzeros  = (const u32*)d_in[2];
    const float* scales  = (const float*)d_in[3];
    const float* bias    = (const float*)d_in[4];
    float* out = (float*)d_out;

    __bf16* W   = (__bf16*)d_ws;                                     // 32 MB
    __bf16* Abf = (__bf16*)((char*)d_ws + (size_t)OUT_F * IN_F * 2); // 32 MB

    prep_kernel<<<dim3(DEQ_BLOCKS + CVT_BLOCKS), dim3(256), 0, stream>>>(
        qweight, qzeros, scales, x, W, Abf);
    gemm8p<<<dim3(256), dim3(512), 0, stream>>>(Abf, W, bias, out);
}